// Round 19
// baseline (193.571 us; speedup 1.0000x reference)
//
#include <hip/hip_runtime.h>
#include <hip/hip_bf16.h>

// Problem constants
#define Bb 2
#define Nn 4096
#define Cc 1024
#define Hh 16
#define Dd 64
#define Mm (Bb*Nn)      // 8192
#define W2 10
#define WINSZ 21        // 2*W2+1

typedef __attribute__((ext_vector_type(8))) short  bf16x8s;
typedef __attribute__((ext_vector_type(4))) float  f32x4;
typedef __attribute__((ext_vector_type(4))) unsigned short us4;

#define AS1 __attribute__((address_space(1)))
#define AS3 __attribute__((address_space(3)))

__device__ __forceinline__ unsigned short f2bf(float f) {
  unsigned int u = __float_as_uint(f);
  u += 0x7FFFu + ((u >> 16) & 1u);
  return (unsigned short)(u >> 16);
}
__device__ __forceinline__ float bflo(unsigned int u) { return __uint_as_float(u << 16); }
__device__ __forceinline__ float bfhi(unsigned int u) { return __uint_as_float(u & 0xFFFF0000u); }

__device__ __forceinline__ us4 cvt4(float4 v) {
  us4 o;
  o.x = f2bf(v.x); o.y = f2bf(v.y); o.z = f2bf(v.z); o.w = f2bf(v.w);
  return o;
}

// ---------------- fused fp32->bf16 converts + bias gather (one launch) ----------------
__global__ __launch_bounds__(256) void cvt_all(const float4* __restrict__ q,
                                               const float4* __restrict__ wq,
                                               const float4* __restrict__ wk,
                                               const float4* __restrict__ wv,
                                               const float4* __restrict__ wo,
                                               const float* __restrict__ bq,
                                               const float* __restrict__ bk,
                                               const float* __restrict__ bv,
                                               us4* __restrict__ qb4,
                                               us4* __restrict__ wqkv4,
                                               us4* __restrict__ wo4,
                                               float* __restrict__ bqkv) {
  const int NQ = 2097152, NW = 262144, TOT = NQ + 4 * NW;
  const int gid = blockIdx.x * 256 + threadIdx.x;
  const int stride = gridDim.x * 256;
  for (int i = gid; i < TOT; i += stride) {
    if (i < NQ) {
      qb4[i] = cvt4(q[i]);
    } else {
      int j = i - NQ;
      int r = j >> 18, k = j & (NW - 1);
      if (r == 0)      wqkv4[k]          = cvt4(wq[k]);
      else if (r == 1) wqkv4[NW + k]     = cvt4(wk[k]);
      else if (r == 2) wqkv4[2 * NW + k] = cvt4(wv[k]);
      else             wo4[k]            = cvt4(wo[k]);
    }
  }
  if (gid < 3072) {
    float v = (gid < 1024) ? bq[gid] : (gid < 2048) ? bk[gid - 1024] : bv[gid - 2048];
    bqkv[gid] = v;
  }
}

// ---------------- 128x256 flight-2 pipelined bf16 NT GEMM (K=1024) — R10-proven ----------------
template<bool OUT_BF16>
__global__ __launch_bounds__(512) void gemm_p3(const unsigned short* __restrict__ A,
                                               const unsigned short* __restrict__ Bm,
                                               const float* __restrict__ bias,
                                               void* __restrict__ Cout,
                                               int N) {
  constexpr int K = 1024, NT = 16;
  __shared__ unsigned short lds[3][24576];   // 144 KB

  const int tid = threadIdx.x, wid = tid >> 6, lane = tid & 63;
  const int wm = wid >> 2, wn = wid & 3;

  const int nwg = gridDim.x, cpx = nwg >> 3, bid = blockIdx.x;
  const int swz = (bid & 7) * cpx + (bid >> 3);
  constexpr int NBM = Mm / 128;   // 64
  const int m0 = (swz % NBM) << 7, n0 = (swz / NBM) << 8;

  const int rbase = wid * 8 + (lane >> 3);
  const int cst = ((lane & 7) ^ (lane >> 3)) * 8;
  const unsigned short* aS0 = A + (size_t)(m0 + rbase) * K + cst;
  const unsigned short* aS1 = A + (size_t)(m0 + 64 + rbase) * K + cst;
  const unsigned short* bS0 = Bm + (size_t)(n0 + rbase) * K + cst;
  const unsigned short* bS1 = Bm + (size_t)(n0 + 64 + rbase) * K + cst;
  const unsigned short* bS2 = Bm + (size_t)(n0 + 128 + rbase) * K + cst;
  const unsigned short* bS3 = Bm + (size_t)(n0 + 192 + rbase) * K + cst;
  const int dA0 = wid * 512, dA1 = 4096 + wid * 512;
  const int dB0 = 8192 + wid * 512, dB1 = 12288 + wid * 512;
  const int dB2 = 16384 + wid * 512, dB3 = 20480 + wid * 512;

#define STG(bf, kt) do {                                                                   \
    const size_t ko = (size_t)(kt) * 64;                                                   \
    __builtin_amdgcn_global_load_lds((AS1 const void*)(aS0 + ko), (AS3 void*)(&lds[bf][dA0]), 16, 0, 0); \
    __builtin_amdgcn_global_load_lds((AS1 const void*)(aS1 + ko), (AS3 void*)(&lds[bf][dA1]), 16, 0, 0); \
    __builtin_amdgcn_global_load_lds((AS1 const void*)(bS0 + ko), (AS3 void*)(&lds[bf][dB0]), 16, 0, 0); \
    __builtin_amdgcn_global_load_lds((AS1 const void*)(bS1 + ko), (AS3 void*)(&lds[bf][dB1]), 16, 0, 0); \
    __builtin_amdgcn_global_load_lds((AS1 const void*)(bS2 + ko), (AS3 void*)(&lds[bf][dB2]), 16, 0, 0); \
    __builtin_amdgcn_global_load_lds((AS1 const void*)(bS3 + ko), (AS3 void*)(&lds[bf][dB3]), 16, 0, 0); \
  } while (0)

  int aoff[2][4], boff[2][4];
#pragma unroll
  for (int kk = 0; kk < 2; ++kk) {
    const int chs = ((kk * 4 + (lane >> 4)) ^ (lane & 7)) * 8;
#pragma unroll
    for (int f = 0; f < 4; ++f) {
      aoff[kk][f] = (wm * 64 + f * 16 + (lane & 15)) * 64 + chs;
      boff[kk][f] = 8192 + (wn * 64 + f * 16 + (lane & 15)) * 64 + chs;
    }
  }

  f32x4 acc[4][4] = {};

  STG(0, 0);
  STG(1, 1);
  asm volatile("s_waitcnt vmcnt(6)" ::: "memory");
  __builtin_amdgcn_sched_barrier(0);
  __builtin_amdgcn_s_barrier();
  __builtin_amdgcn_sched_barrier(0);

  int cur = 0, stg = 2;
  for (int t = 0; t < NT; ++t) {
    if (t + 2 < NT) STG(stg, t + 2);

    const unsigned short* L = &lds[cur][0];
    bf16x8s a[2][4], b[2][4];
#pragma unroll
    for (int kk = 0; kk < 2; ++kk) {
#pragma unroll
      for (int f = 0; f < 4; ++f) {
        a[kk][f] = *(const bf16x8s*)(L + aoff[kk][f]);
        b[kk][f] = *(const bf16x8s*)(L + boff[kk][f]);
      }
    }
    __builtin_amdgcn_s_setprio(1);
#pragma unroll
    for (int kk = 0; kk < 2; ++kk)
#pragma unroll
      for (int fm = 0; fm < 4; ++fm)
#pragma unroll
        for (int fn = 0; fn < 4; ++fn)
          acc[fm][fn] = __builtin_amdgcn_mfma_f32_16x16x32_bf16(a[kk][fm], b[kk][fn], acc[fm][fn], 0, 0, 0);
    __builtin_amdgcn_s_setprio(0);

    if (t + 1 < NT) {
      if (t + 2 < NT) asm volatile("s_waitcnt vmcnt(6)" ::: "memory");
      else            asm volatile("s_waitcnt vmcnt(0)" ::: "memory");
      __builtin_amdgcn_sched_barrier(0);
      __builtin_amdgcn_s_barrier();
      __builtin_amdgcn_sched_barrier(0);
    }
    cur = (cur == 2) ? 0 : cur + 1;
    stg = (stg == 2) ? 0 : stg + 1;
  }
#undef STG

  const int r0 = m0 + wm * 64 + (lane >> 4) * 4;
  const int c0 = n0 + wn * 64 + (lane & 15);
#pragma unroll
  for (int fm = 0; fm < 4; ++fm) {
#pragma unroll
    for (int fn = 0; fn < 4; ++fn) {
      const int col = c0 + fn * 16;
      const float bv = bias[col];
#pragma unroll
      for (int r = 0; r < 4; ++r) {
        const int row = r0 + fm * 16 + r;
        const float v = acc[fm][fn][r] + bv;
        if (OUT_BF16)
          ((unsigned short*)Cout)[(size_t)row * N + col] = f2bf(v);
        else
          ((float*)Cout)[(size_t)row * N + col] = v;
      }
    }
  }
}

// ---------------- banded local attention: quad of 4 threads handles 2 rows ----------------
// 256 threads = 64 quads = 128 rows per block. Each thread owns a d-quarter of
// TWO consecutive rows; the 22-row union K/V window is read ONCE and FMA'd into
// both rows' scores -> LDS read traffic per row drops 42 -> 22 chunks (-48%).
#define TN 128
#define KVROWS (TN + 2 * W2)   // 148 staged rows

__global__ void attn_kernel(const unsigned short* __restrict__ QKV, // [Mm][3072]
                            unsigned short* __restrict__ AO,        // [Mm][1024]
                            float* __restrict__ attn_last) {        // [Bb*Hh*11]
  __shared__ uint4 Kl[KVROWS * 8];
  __shared__ uint4 Vl[KVROWS * 8];

  const int nt = Nn / TN;            // 32
  const int bid = blockIdx.x;
  const int tile = bid & (nt - 1);
  const int bh = bid / nt;
  const int h = bh & (Hh - 1), b = bh / Hh;
  const int n0 = tile * TN;
  const int tid = threadIdx.x;

  // stage K,V rows [n0-10, n0+137], zero-fill OOB, swizzled chunk placement
  for (int idx = tid; idx < KVROWS * 8; idx += 256) {
    const int r = idx >> 3, c = idx & 7;
    const int pos = n0 - W2 + r;
    uint4 kv = make_uint4(0, 0, 0, 0), vv = make_uint4(0, 0, 0, 0);
    if (pos >= 0 && pos < Nn) {
      const uint4* row = (const uint4*)(QKV + (size_t)(b * Nn + pos) * 3072);
      kv = row[128 + h * 8 + c];
      vv = row[256 + h * 8 + c];
    }
    const int slot = c ^ (r & 7);
    Kl[r * 8 + slot] = kv;
    Vl[r * 8 + slot] = vv;
  }
  __syncthreads();

  const int quad = tid >> 2;       // 0..63
  const int qtr  = tid & 3;        // d-quarter (16 elems = 2 chunks)
  const int rA = 2 * quad;         // local rows rA, rA+1
  const int nA = n0 + rA, nB = nA + 1;
  const size_t mA = (size_t)b * Nn + nA;
  const size_t mB = mA + 1;

  // q quarter-rows, packed (2 uint4 each)
  const uint4* qrowA = (const uint4*)(QKV + mA * 3072) + h * 8 + qtr * 2;
  const uint4* qrowB = (const uint4*)(QKV + mB * 3072) + h * 8 + qtr * 2;
  const uint4 qa0 = qrowA[0], qa1 = qrowA[1];
  const uint4 qb0 = qrowB[0], qb1 = qrowB[1];

  float pA[WINSZ], pB[WINSZ];
#pragma unroll
  for (int w = 0; w < WINSZ; ++w) { pA[w] = 0.f; pB[w] = 0.f; }

  // scores: c-outer (2 chunks), union-window inner (22 positions, shared reads)
#pragma unroll
  for (int c = 0; c < 2; ++c) {
    const uint4 qav = (c == 0) ? qa0 : qa1;
    const uint4 qbv = (c == 0) ? qb0 : qb1;
    const float a0 = bflo(qav.x), a1 = bfhi(qav.x), a2 = bflo(qav.y), a3 = bfhi(qav.y);
    const float a4 = bflo(qav.z), a5 = bfhi(qav.z), a6 = bflo(qav.w), a7 = bfhi(qav.w);
    const float b0 = bflo(qbv.x), b1 = bfhi(qbv.x), b2 = bflo(qbv.y), b3 = bfhi(qbv.y);
    const float b4 = bflo(qbv.z), b5 = bfhi(qbv.z), b6 = bflo(qbv.w), b7 = bfhi(qbv.w);
#pragma unroll 11
    for (int u = 0; u < WINSZ + 1; ++u) {     // 22 union positions
      const int r = rA + u;
      const uint4 v = Kl[r * 8 + ((qtr * 2 + c) ^ (r & 7))];
      const float e0 = bflo(v.x), e1 = bfhi(v.x), e2 = bflo(v.y), e3 = bfhi(v.y);
      const float e4 = bflo(v.z), e5 = bfhi(v.z), e6 = bflo(v.w), e7 = bfhi(v.w);
      if (u < WINSZ) {
        float s0 = a0 * e0 + a2 * e2, s1 = a1 * e1 + a3 * e3;
        s0 += a4 * e4 + a6 * e6;
        s1 += a5 * e5 + a7 * e7;
        pA[u] += s0 + s1;
      }
      if (u >= 1) {
        float s0 = b0 * e0 + b2 * e2, s1 = b1 * e1 + b3 * e3;
        s0 += b4 * e4 + b6 * e6;
        s1 += b5 * e5 + b7 * e7;
        pB[u - 1] += s0 + s1;
      }
    }
  }

  // combine quarters (4-lane group) + scale + mask + softmax for both rows
#pragma unroll
  for (int w = 0; w < WINSZ; ++w) {
    float tA = pA[w];
    tA += __shfl_xor(tA, 1, 64);
    tA += __shfl_xor(tA, 2, 64);
    const int posA = nA - W2 + w;
    pA[w] = (posA < 0 || posA >= Nn) ? -1e30f : tA * 0.125f;
    float tB = pB[w];
    tB += __shfl_xor(tB, 1, 64);
    tB += __shfl_xor(tB, 2, 64);
    const int posB = nB - W2 + w;
    pB[w] = (posB < 0 || posB >= Nn) ? -1e30f : tB * 0.125f;
  }
  float mxA = pA[0], mxB = pB[0];
#pragma unroll
  for (int w = 1; w < WINSZ; ++w) { mxA = fmaxf(mxA, pA[w]); mxB = fmaxf(mxB, pB[w]); }
  float sumA = 0.f, sumB = 0.f;
#pragma unroll
  for (int w = 0; w < WINSZ; ++w) {
    pA[w] = __expf(pA[w] - mxA); sumA += pA[w];
    pB[w] = __expf(pB[w] - mxB); sumB += pB[w];
  }
  const float invA = 1.0f / sumA, invB = 1.0f / sumB;

  if (nB == Nn - 1 && qtr == 0) {
#pragma unroll
    for (int w = 0; w <= W2; ++w)
      attn_last[(b * Hh + h) * (W2 + 1) + w] = pB[w] * invB;
  }

  // P·V for both rows over this thread's d-quarter (2 chunks), shared V reads
  uint4* orowA = (uint4*)(AO + mA * Cc + h * Dd) + qtr * 2;
  uint4* orowB = (uint4*)(AO + mB * Cc + h * Dd) + qtr * 2;
#pragma unroll
  for (int c = 0; c < 2; ++c) {
    float oA0 = 0.f, oA1 = 0.f, oA2 = 0.f, oA3 = 0.f, oA4 = 0.f, oA5 = 0.f, oA6 = 0.f, oA7 = 0.f;
    float oB0 = 0.f, oB1 = 0.f, oB2 = 0.f, oB3 = 0.f, oB4 = 0.f, oB5 = 0.f, oB6 = 0.f, oB7 = 0.f;
#pragma unroll 11
    for (int u = 0; u < WINSZ + 1; ++u) {
      const int r = rA + u;
      const uint4 v = Vl[r * 8 + ((qtr * 2 + c) ^ (r & 7))];
      const float e0 = bflo(v.x), e1 = bfhi(v.x), e2 = bflo(v.y), e3 = bfhi(v.y);
      const float e4 = bflo(v.z), e5 = bfhi(v.z), e6 = bflo(v.w), e7 = bfhi(v.w);
      if (u < WINSZ) {
        const float pw = pA[u];
        oA0 += pw * e0; oA1 += pw * e1; oA2 += pw * e2; oA3 += pw * e3;
        oA4 += pw * e4; oA5 += pw * e5; oA6 += pw * e6; oA7 += pw * e7;
      }
      if (u >= 1) {
        const float pw = pB[u - 1];
        oB0 += pw * e0; oB1 += pw * e1; oB2 += pw * e2; oB3 += pw * e3;
        oB4 += pw * e4; oB5 += pw * e5; oB6 += pw * e6; oB7 += pw * e7;
      }
    }
    unsigned int dA0 = (unsigned int)f2bf(oA0 * invA) | ((unsigned int)f2bf(oA1 * invA) << 16);
    unsigned int dA1 = (unsigned int)f2bf(oA2 * invA) | ((unsigned int)f2bf(oA3 * invA) << 16);
    unsigned int dA2 = (unsigned int)f2bf(oA4 * invA) | ((unsigned int)f2bf(oA5 * invA) << 16);
    unsigned int dA3 = (unsigned int)f2bf(oA6 * invA) | ((unsigned int)f2bf(oA7 * invA) << 16);
    orowA[c] = make_uint4(dA0, dA1, dA2, dA3);
    unsigned int dB0 = (unsigned int)f2bf(oB0 * invB) | ((unsigned int)f2bf(oB1 * invB) << 16);
    unsigned int dB1 = (unsigned int)f2bf(oB2 * invB) | ((unsigned int)f2bf(oB3 * invB) << 16);
    unsigned int dB2 = (unsigned int)f2bf(oB4 * invB) | ((unsigned int)f2bf(oB5 * invB) << 16);
    unsigned int dB3 = (unsigned int)f2bf(oB6 * invB) | ((unsigned int)f2bf(oB7 * invB) << 16);
    orowB[c] = make_uint4(dB0, dB1, dB2, dB3);
  }
}

// ---------------- launch ----------------
extern "C" void kernel_launch(void* const* d_in, const int* in_sizes, int n_in,
                              void* d_out, int out_size, void* d_ws, size_t ws_size,
                              hipStream_t stream) {
  const float* q    = (const float*)d_in[0];
  const float* Wq_w = (const float*)d_in[1];
  const float* Wq_b = (const float*)d_in[2];
  const float* Wk_w = (const float*)d_in[3];
  const float* Wk_b = (const float*)d_in[4];
  const float* Wv_w = (const float*)d_in[5];
  const float* Wv_b = (const float*)d_in[6];
  const float* Wo_w = (const float*)d_in[7];
  const float* Wo_b = (const float*)d_in[8];
  float* out = (float*)d_out;                       // [Mm*Cc] + [Bb*Hh*11]
  float* attn_last = out + (size_t)Mm * Cc;

  // workspace carve (bytes)
  char* ws = (char*)d_ws;
  unsigned short* qb   = (unsigned short*)(ws);                       // 16 MB
  unsigned short* Wqkv = (unsigned short*)(ws + 16777216);            // 6 MB
  unsigned short* Wo16 = (unsigned short*)(ws + 16777216 + 6291456);  // 2 MB
  float*          bqkv = (float*)(ws + 25165824);                     // 3072 f32
  unsigned short* QKV  = (unsigned short*)(ws + 25182208);            // 48 MB
  unsigned short* AO   = (unsigned short*)(ws + 75513856);            // 16 MB

  // 1) fused converts (q, Wq, Wk, Wv, Wo) + bias gather — one launch
  cvt_all<<<2048, 256, 0, stream>>>((const float4*)q,
                                    (const float4*)Wq_w, (const float4*)Wk_w,
                                    (const float4*)Wv_w, (const float4*)Wo_w,
                                    Wq_b, Wk_b, Wv_b,
                                    (us4*)qb, (us4*)Wqkv, (us4*)Wo16, bqkv);

  // 2) fused QKV projection: [8192,1024] x [3072,1024]^T -> bf16 [8192,3072]
  {
    dim3 grid((Mm / 128) * (3072 / 256));   // 768, %8==0, 3 balanced rounds
    gemm_p3<true><<<grid, 512, 0, stream>>>(qb, Wqkv, bqkv, (void*)QKV, 3072);
  }

  // 3) windowed attention -> bf16 [8192,1024] + attn_last tail of d_out
  {
    dim3 grid(Bb * Hh * (Nn / TN));          // 1024 blocks x 256 thr
    attn_kernel<<<grid, 256, 0, stream>>>(QKV, AO, attn_last);
  }

  // 4) output projection: [8192,1024] x [1024,1024]^T -> fp32 d_out
  {
    dim3 grid((Mm / 128) * (Cc / 256));     // 256, %8==0, 1 balanced round
    gemm_p3<false><<<grid, 512, 0, stream>>>(AO, Wo16, Wo_b, (void*)out, Cc);
  }
}

// Round 20
// 134.179 us; speedup vs baseline: 1.4426x; 1.4426x over previous
//
#include <hip/hip_runtime.h>
#include <hip/hip_bf16.h>

// Problem constants
#define Bb 2
#define Nn 4096
#define Cc 1024
#define Hh 16
#define Dd 64
#define Mm (Bb*Nn)      // 8192
#define W2 10
#define WINSZ 21        // 2*W2+1

typedef __attribute__((ext_vector_type(8))) short  bf16x8s;
typedef __attribute__((ext_vector_type(4))) float  f32x4;
typedef __attribute__((ext_vector_type(4))) unsigned short us4;

#define AS1 __attribute__((address_space(1)))
#define AS3 __attribute__((address_space(3)))

__device__ __forceinline__ unsigned short f2bf(float f) {
  unsigned int u = __float_as_uint(f);
  u += 0x7FFFu + ((u >> 16) & 1u);
  return (unsigned short)(u >> 16);
}
__device__ __forceinline__ float bflo(unsigned int u) { return __uint_as_float(u << 16); }
__device__ __forceinline__ float bfhi(unsigned int u) { return __uint_as_float(u & 0xFFFF0000u); }

__device__ __forceinline__ us4 cvt4(float4 v) {
  us4 o;
  o.x = f2bf(v.x); o.y = f2bf(v.y); o.z = f2bf(v.z); o.w = f2bf(v.w);
  return o;
}

// ---------------- fused fp32->bf16 converts + bias gather (one launch) ----------------
__global__ __launch_bounds__(256) void cvt_all(const float4* __restrict__ q,
                                               const float4* __restrict__ wq,
                                               const float4* __restrict__ wk,
                                               const float4* __restrict__ wv,
                                               const float4* __restrict__ wo,
                                               const float* __restrict__ bq,
                                               const float* __restrict__ bk,
                                               const float* __restrict__ bv,
                                               us4* __restrict__ qb4,
                                               us4* __restrict__ wqkv4,
                                               us4* __restrict__ wo4,
                                               float* __restrict__ bqkv) {
  const int NQ = 2097152, NW = 262144, TOT = NQ + 4 * NW;
  const int gid = blockIdx.x * 256 + threadIdx.x;
  const int stride = gridDim.x * 256;
  for (int i = gid; i < TOT; i += stride) {
    if (i < NQ) {
      qb4[i] = cvt4(q[i]);
    } else {
      int j = i - NQ;
      int r = j >> 18, k = j & (NW - 1);
      if (r == 0)      wqkv4[k]          = cvt4(wq[k]);
      else if (r == 1) wqkv4[NW + k]     = cvt4(wk[k]);
      else if (r == 2) wqkv4[2 * NW + k] = cvt4(wv[k]);
      else             wo4[k]            = cvt4(wo[k]);
    }
  }
  if (gid < 3072) {
    float v = (gid < 1024) ? bq[gid] : (gid < 2048) ? bk[gid - 1024] : bv[gid - 2048];
    bqkv[gid] = v;
  }
}

// ---------------- 128x256 flight-2 pipelined bf16 NT GEMM (K=1024) — R10-proven ----------------
// 8 waves (2M x 4N, per-wave 64x64), BK=64, THREE LDS buffers; tile t reads buf[t%3]
// while STG(t+2) is issued; end-of-tile counted vmcnt(6) + ONE s_barrier.
// Chunk-XOR swizzle; bijective XCD swizzle + column-major tile walk.
template<bool OUT_BF16>
__global__ __launch_bounds__(512) void gemm_p3(const unsigned short* __restrict__ A,
                                               const unsigned short* __restrict__ Bm,
                                               const float* __restrict__ bias,
                                               void* __restrict__ Cout,
                                               int N) {
  constexpr int K = 1024, NT = 16;
  __shared__ unsigned short lds[3][24576];   // 144 KB

  const int tid = threadIdx.x, wid = tid >> 6, lane = tid & 63;
  const int wm = wid >> 2, wn = wid & 3;

  const int nwg = gridDim.x, cpx = nwg >> 3, bid = blockIdx.x;
  const int swz = (bid & 7) * cpx + (bid >> 3);
  constexpr int NBM = Mm / 128;   // 64
  const int m0 = (swz % NBM) << 7, n0 = (swz / NBM) << 8;

  const int rbase = wid * 8 + (lane >> 3);
  const int cst = ((lane & 7) ^ (lane >> 3)) * 8;
  const unsigned short* aS0 = A + (size_t)(m0 + rbase) * K + cst;
  const unsigned short* aS1 = A + (size_t)(m0 + 64 + rbase) * K + cst;
  const unsigned short* bS0 = Bm + (size_t)(n0 + rbase) * K + cst;
  const unsigned short* bS1 = Bm + (size_t)(n0 + 64 + rbase) * K + cst;
  const unsigned short* bS2 = Bm + (size_t)(n0 + 128 + rbase) * K + cst;
  const unsigned short* bS3 = Bm + (size_t)(n0 + 192 + rbase) * K + cst;
  const int dA0 = wid * 512, dA1 = 4096 + wid * 512;
  const int dB0 = 8192 + wid * 512, dB1 = 12288 + wid * 512;
  const int dB2 = 16384 + wid * 512, dB3 = 20480 + wid * 512;

#define STG(bf, kt) do {                                                                   \
    const size_t ko = (size_t)(kt) * 64;                                                   \
    __builtin_amdgcn_global_load_lds((AS1 const void*)(aS0 + ko), (AS3 void*)(&lds[bf][dA0]), 16, 0, 0); \
    __builtin_amdgcn_global_load_lds((AS1 const void*)(aS1 + ko), (AS3 void*)(&lds[bf][dA1]), 16, 0, 0); \
    __builtin_amdgcn_global_load_lds((AS1 const void*)(bS0 + ko), (AS3 void*)(&lds[bf][dB0]), 16, 0, 0); \
    __builtin_amdgcn_global_load_lds((AS1 const void*)(bS1 + ko), (AS3 void*)(&lds[bf][dB1]), 16, 0, 0); \
    __builtin_amdgcn_global_load_lds((AS1 const void*)(bS2 + ko), (AS3 void*)(&lds[bf][dB2]), 16, 0, 0); \
    __builtin_amdgcn_global_load_lds((AS1 const void*)(bS3 + ko), (AS3 void*)(&lds[bf][dB3]), 16, 0, 0); \
  } while (0)

  int aoff[2][4], boff[2][4];
#pragma unroll
  for (int kk = 0; kk < 2; ++kk) {
    const int chs = ((kk * 4 + (lane >> 4)) ^ (lane & 7)) * 8;
#pragma unroll
    for (int f = 0; f < 4; ++f) {
      aoff[kk][f] = (wm * 64 + f * 16 + (lane & 15)) * 64 + chs;
      boff[kk][f] = 8192 + (wn * 64 + f * 16 + (lane & 15)) * 64 + chs;
    }
  }

  f32x4 acc[4][4] = {};

  STG(0, 0);
  STG(1, 1);
  asm volatile("s_waitcnt vmcnt(6)" ::: "memory");
  __builtin_amdgcn_sched_barrier(0);
  __builtin_amdgcn_s_barrier();
  __builtin_amdgcn_sched_barrier(0);

  int cur = 0, stg = 2;
  for (int t = 0; t < NT; ++t) {
    if (t + 2 < NT) STG(stg, t + 2);

    const unsigned short* L = &lds[cur][0];
    bf16x8s a[2][4], b[2][4];
#pragma unroll
    for (int kk = 0; kk < 2; ++kk) {
#pragma unroll
      for (int f = 0; f < 4; ++f) {
        a[kk][f] = *(const bf16x8s*)(L + aoff[kk][f]);
        b[kk][f] = *(const bf16x8s*)(L + boff[kk][f]);
      }
    }
    __builtin_amdgcn_s_setprio(1);
#pragma unroll
    for (int kk = 0; kk < 2; ++kk)
#pragma unroll
      for (int fm = 0; fm < 4; ++fm)
#pragma unroll
        for (int fn = 0; fn < 4; ++fn)
          acc[fm][fn] = __builtin_amdgcn_mfma_f32_16x16x32_bf16(a[kk][fm], b[kk][fn], acc[fm][fn], 0, 0, 0);
    __builtin_amdgcn_s_setprio(0);

    if (t + 1 < NT) {
      if (t + 2 < NT) asm volatile("s_waitcnt vmcnt(6)" ::: "memory");
      else            asm volatile("s_waitcnt vmcnt(0)" ::: "memory");
      __builtin_amdgcn_sched_barrier(0);
      __builtin_amdgcn_s_barrier();
      __builtin_amdgcn_sched_barrier(0);
    }
    cur = (cur == 2) ? 0 : cur + 1;
    stg = (stg == 2) ? 0 : stg + 1;
  }
#undef STG

  const int r0 = m0 + wm * 64 + (lane >> 4) * 4;
  const int c0 = n0 + wn * 64 + (lane & 15);
#pragma unroll
  for (int fm = 0; fm < 4; ++fm) {
#pragma unroll
    for (int fn = 0; fn < 4; ++fn) {
      const int col = c0 + fn * 16;
      const float bv = bias[col];
#pragma unroll
      for (int r = 0; r < 4; ++r) {
        const int row = r0 + fm * 16 + r;
        const float v = acc[fm][fn][r] + bv;
        if (OUT_BF16)
          ((unsigned short*)Cout)[(size_t)row * N + col] = f2bf(v);
        else
          ((float*)Cout)[(size_t)row * N + col] = v;
      }
    }
  }
}

// ---------------- banded local attention: 4 threads per (b,h,n) row ----------------
// 512 threads = 128 rows per block; each thread owns a d-quarter (16 elems).
#define TN 128
#define KVROWS (TN + 2 * W2)   // 148 staged rows

__global__ __launch_bounds__(512) void attn_kernel(const unsigned short* __restrict__ QKV, // [Mm][3072]
                                                   unsigned short* __restrict__ AO,        // [Mm][1024]
                                                   float* __restrict__ attn_last) {        // [Bb*Hh*11]
  __shared__ uint4 Kl[KVROWS * 8];
  __shared__ uint4 Vl[KVROWS * 8];

  const int nt = Nn / TN;            // 32
  const int bid = blockIdx.x;
  const int tile = bid & (nt - 1);
  const int bh = bid / nt;
  const int h = bh & (Hh - 1), b = bh / Hh;
  const int n0 = tile * TN;
  const int tid = threadIdx.x;

  // stage K,V rows [n0-10, n0+137], zero-fill OOB, swizzled chunk placement
  for (int idx = tid; idx < KVROWS * 8; idx += 512) {
    const int r = idx >> 3, c = idx & 7;
    const int pos = n0 - W2 + r;
    uint4 kv = make_uint4(0, 0, 0, 0), vv = make_uint4(0, 0, 0, 0);
    if (pos >= 0 && pos < Nn) {
      const uint4* row = (const uint4*)(QKV + (size_t)(b * Nn + pos) * 3072);
      kv = row[128 + h * 8 + c];
      vv = row[256 + h * 8 + c];
    }
    const int slot = c ^ (r & 7);
    Kl[r * 8 + slot] = kv;
    Vl[r * 8 + slot] = vv;
  }
  __syncthreads();

  const int row = tid >> 2;        // 0..127
  const int qtr = tid & 3;         // d-quarter (16 elems = 2 chunks)
  const int n = n0 + row;
  const size_t m = (size_t)b * Nn + n;

  // q quarter-row, packed (2 uint4 = 8 regs)
  const uint4* qrow = (const uint4*)(QKV + m * 3072) + h * 8 + qtr * 2;
  const uint4 qd0 = qrow[0], qd1 = qrow[1];

  float p[WINSZ];
#pragma unroll
  for (int w = 0; w < WINSZ; ++w) p[w] = 0.f;

  // scores: c-outer (2 chunks), w-inner
#pragma unroll
  for (int c = 0; c < 2; ++c) {
    const uint4 qv = (c == 0) ? qd0 : qd1;
    const float q0 = bflo(qv.x), q1 = bfhi(qv.x);
    const float q2 = bflo(qv.y), q3 = bfhi(qv.y);
    const float q4 = bflo(qv.z), q5 = bfhi(qv.z);
    const float q6 = bflo(qv.w), q7 = bfhi(qv.w);
#pragma unroll 7
    for (int w = 0; w < WINSZ; ++w) {
      const int r = row + w;
      const uint4 v = Kl[r * 8 + ((qtr * 2 + c) ^ (r & 7))];
      float a0 = q0 * bflo(v.x);
      float a1 = q1 * bfhi(v.x);
      a0 += q2 * bflo(v.y);
      a1 += q3 * bfhi(v.y);
      a0 += q4 * bflo(v.z);
      a1 += q5 * bfhi(v.z);
      a0 += q6 * bflo(v.w);
      a1 += q7 * bfhi(v.w);
      p[w] += a0 + a1;
    }
  }

  // combine quarters (4-lane group) + scale + mask + softmax
#pragma unroll
  for (int w = 0; w < WINSZ; ++w) {
    float t = p[w];
    t += __shfl_xor(t, 1, 64);
    t += __shfl_xor(t, 2, 64);
    const int pos = n - W2 + w;
    p[w] = (pos < 0 || pos >= Nn) ? -1e30f : t * 0.125f;   // 1/sqrt(64)
  }
  float mx = p[0];
#pragma unroll
  for (int w = 1; w < WINSZ; ++w) mx = fmaxf(mx, p[w]);
  float sum = 0.f;
#pragma unroll
  for (int w = 0; w < WINSZ; ++w) { p[w] = __expf(p[w] - mx); sum += p[w]; }
  const float inv = 1.0f / sum;

  if (n == Nn - 1 && qtr == 0) {
#pragma unroll
    for (int w = 0; w <= W2; ++w)
      attn_last[(b * Hh + h) * (W2 + 1) + w] = p[w] * inv;
  }

  // P·V over this thread's d-quarter (2 chunks of 8), store immediately
  uint4* orow = (uint4*)(AO + m * Cc + h * Dd) + qtr * 2;
#pragma unroll
  for (int c = 0; c < 2; ++c) {
    float o0 = 0.f, o1 = 0.f, o2 = 0.f, o3 = 0.f;
    float o4 = 0.f, o5 = 0.f, o6 = 0.f, o7 = 0.f;
#pragma unroll 7
    for (int w = 0; w < WINSZ; ++w) {
      const int r = row + w;
      const uint4 v = Vl[r * 8 + ((qtr * 2 + c) ^ (r & 7))];
      const float pw = p[w];
      o0 += pw * bflo(v.x);
      o1 += pw * bfhi(v.x);
      o2 += pw * bflo(v.y);
      o3 += pw * bfhi(v.y);
      o4 += pw * bflo(v.z);
      o5 += pw * bfhi(v.z);
      o6 += pw * bflo(v.w);
      o7 += pw * bfhi(v.w);
    }
    unsigned int d0 = (unsigned int)f2bf(o0 * inv) | ((unsigned int)f2bf(o1 * inv) << 16);
    unsigned int d1 = (unsigned int)f2bf(o2 * inv) | ((unsigned int)f2bf(o3 * inv) << 16);
    unsigned int d2 = (unsigned int)f2bf(o4 * inv) | ((unsigned int)f2bf(o5 * inv) << 16);
    unsigned int d3 = (unsigned int)f2bf(o6 * inv) | ((unsigned int)f2bf(o7 * inv) << 16);
    orow[c] = make_uint4(d0, d1, d2, d3);
  }
}

// ---------------- launch ----------------
extern "C" void kernel_launch(void* const* d_in, const int* in_sizes, int n_in,
                              void* d_out, int out_size, void* d_ws, size_t ws_size,
                              hipStream_t stream) {
  const float* q    = (const float*)d_in[0];
  const float* Wq_w = (const float*)d_in[1];
  const float* Wq_b = (const float*)d_in[2];
  const float* Wk_w = (const float*)d_in[3];
  const float* Wk_b = (const float*)d_in[4];
  const float* Wv_w = (const float*)d_in[5];
  const float* Wv_b = (const float*)d_in[6];
  const float* Wo_w = (const float*)d_in[7];
  const float* Wo_b = (const float*)d_in[8];
  float* out = (float*)d_out;                       // [Mm*Cc] + [Bb*Hh*11]
  float* attn_last = out + (size_t)Mm * Cc;

  // workspace carve (bytes)
  char* ws = (char*)d_ws;
  unsigned short* qb   = (unsigned short*)(ws);                       // 16 MB
  unsigned short* Wqkv = (unsigned short*)(ws + 16777216);            // 6 MB
  unsigned short* Wo16 = (unsigned short*)(ws + 16777216 + 6291456);  // 2 MB
  float*          bqkv = (float*)(ws + 25165824);                     // 3072 f32
  unsigned short* QKV  = (unsigned short*)(ws + 25182208);            // 48 MB
  unsigned short* AO   = (unsigned short*)(ws + 75513856);            // 16 MB

  // 1) fused converts (q, Wq, Wk, Wv, Wo) + bias gather — one launch
  cvt_all<<<2048, 256, 0, stream>>>((const float4*)q,
                                    (const float4*)Wq_w, (const float4*)Wk_w,
                                    (const float4*)Wv_w, (const float4*)Wo_w,
                                    Wq_b, Wk_b, Wv_b,
                                    (us4*)qb, (us4*)Wqkv, (us4*)Wo16, bqkv);

  // 2) fused QKV projection: [8192,1024] x [3072,1024]^T -> bf16 [8192,3072]
  {
    dim3 grid((Mm / 128) * (3072 / 256));   // 768, %8==0
    gemm_p3<true><<<grid, 512, 0, stream>>>(qb, Wqkv, bqkv, (void*)QKV, 3072);
  }

  // 3) windowed attention -> bf16 [8192,1024] + attn_last tail of d_out
  {
    dim3 grid(Bb * Hh * (Nn / TN));          // 1024 blocks x 512 thr
    attn_kernel<<<grid, 512, 0, stream>>>(QKV, AO, attn_last);
  }

  // 4) output projection: [8192,1024] x [1024,1024]^T -> fp32 d_out
  {
    dim3 grid((Mm / 128) * (Cc / 256));     // 256, %8==0
    gemm_p3<false><<<grid, 512, 0, stream>>>(AO, Wo16, Wo_b, (void*)out, Cc);
  }
}